// Round 1
// baseline (36.179 us; speedup 1.0000x reference)
//
#include <hip/hip_runtime.h>
#include <hip/hip_bf16.h>

// GraphAttentionLayer_8804682957287
//
// Key insight: reference applies softmax to the CONSTANT zero_vec (-9e15),
// not to e. attention == uniform 1/N, so:
//   out[i,:] = relu( mean_r (h @ W)[r,:] ) = relu( ((colsum h) @ W) / N )
// identical for every row i. adj (256 MB), a, and the leaky_relu(e) term are
// dead code. Total traffic: read h (16 MB) + W (128 KB), write out (2 MB).

constexpr int NROWS = 8192;
constexpr int FIN   = 512;
constexpr int FOUT  = 64;

constexpr int PBLOCKS        = 128;           // partial-colsum blocks
constexpr int ROWS_PER_BLOCK = NROWS / PBLOCKS; // 64

// ---------------------------------------------------------------------------
// K1: partial column sums of h (8192 x 512 fp32), float4-vectorized.
// Grid: PBLOCKS blocks x 512 threads. Thread = (j = float4-column 0..127,
// ty = row phase 0..3). Each block owns 64 rows; coalesced 16B/lane loads.
// Output partial[b*512 + c] = sum over block b's rows of h[:, c].
// ---------------------------------------------------------------------------
__global__ __launch_bounds__(512) void colsum_partial_k(
    const float4* __restrict__ h4, float4* __restrict__ partial4)
{
    const int j  = threadIdx.x & 127;   // float4 column
    const int ty = threadIdx.x >> 7;    // 0..3 row phase
    const int b  = blockIdx.x;

    const float4* p = h4 + (size_t)(b * ROWS_PER_BLOCK + ty) * (FIN / 4) + j;
    float4 acc = make_float4(0.f, 0.f, 0.f, 0.f);
    #pragma unroll
    for (int k = 0; k < ROWS_PER_BLOCK / 4; ++k) {
        float4 v = p[(size_t)(4 * k) * (FIN / 4)];
        acc.x += v.x; acc.y += v.y; acc.z += v.z; acc.w += v.w;
    }

    __shared__ float4 sm[512];
    sm[threadIdx.x] = acc;
    __syncthreads();

    if (ty == 0) {
        float4 a0 = sm[j], a1 = sm[128 + j], a2 = sm[256 + j], a3 = sm[384 + j];
        float4 r = make_float4(a0.x + a1.x + a2.x + a3.x,
                               a0.y + a1.y + a2.y + a3.y,
                               a0.z + a1.z + a2.z + a3.z,
                               a0.w + a1.w + a2.w + a3.w);
        partial4[b * (FIN / 4) + j] = r;   // linear layout == scalar [b*512 + c]
    }
}

// ---------------------------------------------------------------------------
// K2: reduce PBLOCKS partials per column -> s[512]; then threads 0..63 do the
// 512-long dot with W[:, t] (W row-major (512,64)), scale by 1/N, relu.
// One block, 512 threads. Deterministic sequential fp32 reduction.
// ---------------------------------------------------------------------------
__global__ __launch_bounds__(512) void reduce_project_k(
    const float* __restrict__ partial, const float* __restrict__ W,
    float* __restrict__ vec)
{
    __shared__ float s[FIN];
    const int t = threadIdx.x;

    float acc = 0.f;
    #pragma unroll 8
    for (int b = 0; b < PBLOCKS; ++b)
        acc += partial[b * FIN + t];
    s[t] = acc;
    __syncthreads();

    if (t < FOUT) {
        float v = 0.f;
        #pragma unroll 8
        for (int c = 0; c < FIN; ++c)
            v += s[c] * W[c * FOUT + t];
        v *= (1.0f / (float)NROWS);
        vec[t] = v > 0.f ? v : 0.f;
    }
}

// ---------------------------------------------------------------------------
// K3: broadcast 64-float vector to all 8192 rows. float4 stores, 2 MB write.
// 131072 float4 elements = 512 blocks x 256 threads.
// ---------------------------------------------------------------------------
__global__ __launch_bounds__(256) void broadcast_k(
    const float4* __restrict__ vec4, float4* __restrict__ out4)
{
    const int i = blockIdx.x * 256 + threadIdx.x;   // 0..131071
    out4[i] = vec4[i & 15];                          // row = i/16, col4 = i%16
}

extern "C" void kernel_launch(void* const* d_in, const int* in_sizes, int n_in,
                              void* d_out, int out_size, void* d_ws, size_t ws_size,
                              hipStream_t stream)
{
    const float* h = (const float*)d_in[0];   // (8192, 512)
    // d_in[1] = adj (8192, 8192) — DEAD, never read
    const float* W = (const float*)d_in[2];   // (512, 64)
    // d_in[3] = a (128, 1)        — DEAD (e is unused by the output)

    float* partial = (float*)d_ws;                       // PBLOCKS*512 floats = 256 KB
    float* vec     = partial + (size_t)PBLOCKS * FIN;    // 64 floats

    colsum_partial_k<<<PBLOCKS, 512, 0, stream>>>(
        (const float4*)h, (float4*)partial);
    reduce_project_k<<<1, 512, 0, stream>>>(partial, W, vec);

    const int n4 = NROWS * FOUT / 4;                     // 131072
    broadcast_k<<<n4 / 256, 256, 0, stream>>>(
        (const float4*)vec, (float4*)d_out);
}

// Round 2
// 13.810 us; speedup vs baseline: 2.6197x; 2.6197x over previous
//
#include <hip/hip_runtime.h>
#include <hip/hip_bf16.h>

// GraphAttentionLayer_8804682957287
//
// Reference applies softmax to the CONSTANT zero_vec (-9e15) => attention is
// uniform 1/N, so out[i,:] = relu(((colsum h) @ W)/N), identical for all rows.
// adj (256 MB) and a are dead. Traffic: read h (16 MB) + W, write out (2 MB).
//
// Round 2: two full-GPU kernels (was 3, with a 128-block K1 and a 1-block K2).
//  K1: 256 blocks; per-block colsum of 32 rows fused with 512x64 projection
//      -> 64-float partial per block (64 KB total in ws).
//  K2: 256 blocks; each block redundantly reduces the 256x64 partials
//      (L2-resident, fixed fp32 order -> identical result in every block),
//      relu(/N), then writes its own 32 rows of the broadcast output.

constexpr int NROWS = 8192;
constexpr int FIN   = 512;
constexpr int FOUT  = 64;

constexpr int BLOCKS         = 256;
constexpr int ROWS_PER_BLOCK = NROWS / BLOCKS;  // 32

// ---------------------------------------------------------------------------
// K1: colsum of 32 rows + projection to 64 outputs, per block.
// 512 threads: (j = float4-col 0..127, ty = row phase 0..3) for the colsum;
// (t = out-col 0..63, ch = chunk 0..7) for the projection.
// ---------------------------------------------------------------------------
__global__ __launch_bounds__(512) void colsum_project_k(
    const float4* __restrict__ h4, const float* __restrict__ W,
    float* __restrict__ ypart)
{
    const int tid = threadIdx.x;
    const int b   = blockIdx.x;

    // --- colsum of this block's 32 rows ---
    const int j  = tid & 127;
    const int ty = tid >> 7;

    const float4* p = h4 + (size_t)(b * ROWS_PER_BLOCK + ty) * (FIN / 4) + j;
    float4 acc = make_float4(0.f, 0.f, 0.f, 0.f);
    #pragma unroll
    for (int k = 0; k < ROWS_PER_BLOCK / 4; ++k) {
        float4 v = p[(size_t)(4 * k) * (FIN / 4)];
        acc.x += v.x; acc.y += v.y; acc.z += v.z; acc.w += v.w;
    }

    __shared__ float4 sm4[512];
    sm4[tid] = acc;
    __syncthreads();

    __shared__ float s[FIN];          // reduced column sums
    if (ty == 0) {
        float4 a0 = sm4[j], a1 = sm4[128 + j], a2 = sm4[256 + j], a3 = sm4[384 + j];
        s[4 * j + 0] = a0.x + a1.x + a2.x + a3.x;
        s[4 * j + 1] = a0.y + a1.y + a2.y + a3.y;
        s[4 * j + 2] = a0.z + a1.z + a2.z + a3.z;
        s[4 * j + 3] = a0.w + a1.w + a2.w + a3.w;
    }
    __syncthreads();

    // --- projection: y_b[t] = sum_c s[c] * W[c*64 + t], split over 8 chunks ---
    const int t  = tid & 63;
    const int ch = tid >> 6;          // 0..7, each covers 64 c-values

    float y = 0.f;
    const int c0 = ch * 64;
    #pragma unroll 8
    for (int i = 0; i < 64; ++i)
        y += s[c0 + i] * W[(c0 + i) * FOUT + t];

    __shared__ float yp[8 * FOUT];
    yp[ch * FOUT + t] = y;
    __syncthreads();

    if (tid < FOUT) {
        float v = 0.f;
        #pragma unroll
        for (int k = 0; k < 8; ++k)
            v += yp[k * FOUT + tid];
        ypart[b * FOUT + tid] = v;
    }
}

// ---------------------------------------------------------------------------
// K2: every block reduces the 256x64 partials identically (deterministic fp32
// order), applies relu(/N), then writes its 32 rows of the broadcast output.
// ---------------------------------------------------------------------------
__global__ __launch_bounds__(512) void finalize_broadcast_k(
    const float* __restrict__ ypart, float4* __restrict__ out4)
{
    const int tid = threadIdx.x;
    const int g   = blockIdx.x;

    // Phase A: thread (t, ch) sums 32 of the 256 block-partials for column t.
    const int t  = tid & 63;
    const int ch = tid >> 6;          // 0..7 chunks of 32 blocks

    float acc = 0.f;
    #pragma unroll 8
    for (int k = 0; k < 32; ++k)
        acc += ypart[(ch * 32 + k) * FOUT + t];

    __shared__ float yp[8 * FOUT];
    yp[ch * FOUT + t] = acc;
    __syncthreads();

    // Phase B: threads 0..63 finish the sum in fixed order, relu(/N).
    __shared__ float4 vec4[FOUT / 4];
    if (tid < FOUT) {
        float v = 0.f;
        #pragma unroll
        for (int k = 0; k < 8; ++k)
            v += yp[k * FOUT + tid];
        v *= (1.0f / (float)NROWS);
        ((float*)vec4)[tid] = v > 0.f ? v : 0.f;
    }
    __syncthreads();

    // Phase C: write 32 rows x 64 cols = 512 float4 (one per thread).
    out4[(size_t)g * 512 + tid] = vec4[tid & 15];
}

extern "C" void kernel_launch(void* const* d_in, const int* in_sizes, int n_in,
                              void* d_out, int out_size, void* d_ws, size_t ws_size,
                              hipStream_t stream)
{
    const float* h = (const float*)d_in[0];   // (8192, 512)
    // d_in[1] = adj (8192, 8192) — DEAD, never read
    const float* W = (const float*)d_in[2];   // (512, 64) row-major
    // d_in[3] = a (128, 1)        — DEAD (e is unused by the output)

    float* ypart = (float*)d_ws;              // 256*64 floats = 64 KB

    colsum_project_k<<<BLOCKS, 512, 0, stream>>>(
        (const float4*)h, W, ypart);
    finalize_broadcast_k<<<BLOCKS, 512, 0, stream>>>(
        ypart, (float4*)d_out);
}